// Round 1
// baseline (4079.055 us; speedup 1.0000x reference)
//
#include <hip/hip_runtime.h>
#include <hip/hip_bf16.h>

// LSTM: B=64, T=256, ID=512, HD=1024. Gates order F,I,A,O along 4H.
// Plan:
//   prep_kernel : fp32->bf16 convert x; transpose+convert Wi->WiT [4H][ID],
//                 Wh->WhT [4H][HD]; zero h0 (bf16) and c (fp32).
//   gates_gemm  : gates[t][b][4H] = bf16(x@Wi + bi), MFMA 16x16x32 bf16,
//                 128x128 tile, stored [T][B][4H] bf16.
//   lstm_step   : per t: g = gates[t] + h@Wh + bh; fused activations + cell
//                 update. 64 blocks; block owns 16 hidden units across all
//                 4 gate chunks; wave w = gate w. h double-buffered bf16.
//   tail_kernel : copy hT (from Q[:,255,:]) and cT into d_out tail.

#define B_  64
#define T_  256
#define ID_ 512
#define HD_ 1024
#define NG_ 4096        // 4*HD
#define M1_ (B_ * T_)   // 16384

typedef __bf16 bf16x8 __attribute__((ext_vector_type(8)));
typedef float  f32x4  __attribute__((ext_vector_type(4)));
typedef int    i32x4  __attribute__((ext_vector_type(4)));
typedef short  s16x4  __attribute__((ext_vector_type(4)));

using bf16 = __hip_bfloat16;

__device__ __forceinline__ float sigmoid_fast(float x) {
    return 1.0f / (1.0f + __expf(-x));
}
__device__ __forceinline__ float tanh_fast(float x) {
    // stable for large |x|; expf overflow -> inf -> 2/inf = 0 -> 1.0
    return 1.0f - 2.0f / (__expf(2.0f * x) + 1.0f);
}

// ---------------------------------------------------------------- prep ----
__global__ __launch_bounds__(256) void prep_kernel(
    const float* __restrict__ x, const float* __restrict__ Wi,
    const float* __restrict__ Wh, bf16* __restrict__ xb,
    bf16* __restrict__ wiT, bf16* __restrict__ whT,
    bf16* __restrict__ h0, float* __restrict__ c) {
    const int tid = blockIdx.x * 256 + threadIdx.x;  // [0, 2097152)

    // x: 4 elems per thread, vectorized read, 8B packed bf16 write
    const float4 v = reinterpret_cast<const float4*>(x)[tid];
    bf16 tmp[4] = { __float2bfloat16(v.x), __float2bfloat16(v.y),
                    __float2bfloat16(v.z), __float2bfloat16(v.w) };
    *reinterpret_cast<s16x4*>(xb + 4 * (size_t)tid) =
        *reinterpret_cast<s16x4*>(tmp);

    // WiT[n][k] = Wi[k][n]  (coalesced writes, strided reads via L2/L3)
    {
        const int n = tid >> 9, k = tid & 511;
        wiT[tid] = __float2bfloat16(Wi[(size_t)k * NG_ + n]);
    }
    // WhT[n][k] = Wh[k][n]: 2 elems per thread
    for (int e = 0; e < 2; ++e) {
        const int idx = 2 * tid + e;
        const int n = idx >> 10, k = idx & 1023;
        whT[idx] = __float2bfloat16(Wh[(size_t)k * NG_ + n]);
    }
    if (tid < B_ * HD_) {
        h0[tid] = __float2bfloat16(0.0f);
        c[tid] = 0.0f;
    }
}

// ---------------------------------------------------- phase-1 gates GEMM ----
// C[M1, NG] = xb[M1, ID] @ WiT[NG, ID]^T + bi ; store bf16 as [T][B][NG]
__global__ __launch_bounds__(256) void gates_gemm_kernel(
    const bf16* __restrict__ xb, const bf16* __restrict__ wiT,
    const float* __restrict__ bi, bf16* __restrict__ gates) {
    __shared__ __align__(16) bf16 As[128 * 40];  // 32+8 pad, 16B-aligned rows
    __shared__ __align__(16) bf16 Bs[128 * 40];
    const int tid  = threadIdx.x;
    const int lane = tid & 63, wave = tid >> 6;
    const int wm = wave >> 1, wn = wave & 1;
    const int l15 = lane & 15, quad = lane >> 4;
    const int row0 = blockIdx.x * 128, col0 = blockIdx.y * 128;

    f32x4 acc[4][4];
    for (int i = 0; i < 4; ++i)
        for (int j = 0; j < 4; ++j) acc[i][j] = f32x4{0.f, 0.f, 0.f, 0.f};

    for (int kt = 0; kt < ID_ / 32; ++kt) {
        const int k0 = kt * 32;
        for (int L = tid; L < 512; L += 256) {
            const int r = L >> 2, s = L & 3;
            *reinterpret_cast<i32x4*>(&As[r * 40 + s * 8]) =
                *reinterpret_cast<const i32x4*>(xb + (size_t)(row0 + r) * ID_ + k0 + s * 8);
            *reinterpret_cast<i32x4*>(&Bs[r * 40 + s * 8]) =
                *reinterpret_cast<const i32x4*>(wiT + (size_t)(col0 + r) * ID_ + k0 + s * 8);
        }
        __syncthreads();
        bf16x8 af[4], bfv[4];
        for (int mt = 0; mt < 4; ++mt)
            af[mt] = *reinterpret_cast<const bf16x8*>(
                &As[(wm * 64 + mt * 16 + l15) * 40 + quad * 8]);
        for (int nt = 0; nt < 4; ++nt)
            bfv[nt] = *reinterpret_cast<const bf16x8*>(
                &Bs[(wn * 64 + nt * 16 + l15) * 40 + quad * 8]);
        for (int mt = 0; mt < 4; ++mt)
            for (int nt = 0; nt < 4; ++nt)
                acc[mt][nt] = __builtin_amdgcn_mfma_f32_16x16x32_bf16(
                    af[mt], bfv[nt], acc[mt][nt], 0, 0, 0);
        __syncthreads();
    }
    // epilogue: +bias, permuted store to [T][B][NG]
    for (int mt = 0; mt < 4; ++mt) {
        for (int nt = 0; nt < 4; ++nt) {
            const int cg = col0 + wn * 64 + nt * 16 + l15;
            const float bias = bi[cg];
            for (int r = 0; r < 4; ++r) {
                const int rg = row0 + wm * 64 + mt * 16 + quad * 4 + r;
                const int b = rg >> 8, t = rg & 255;  // row = b*T + t
                gates[((size_t)(t * 64 + b)) * NG_ + cg] =
                    __float2bfloat16(acc[mt][nt][r] + bias);
            }
        }
    }
}

// ------------------------------------------------------------- LSTM step ----
// 64 blocks x 256 thr. Block owns hidden units [j0, j0+16); wave g handles
// gate chunk g (F,I,A,O). g[b][g*HD+j] = gates_x + h@WhT + bh, then fused
// activations + c/h update through LDS exchange.
__global__ __launch_bounds__(256) void lstm_step_kernel(
    const bf16* __restrict__ gates, const bf16* __restrict__ whT,
    const float* __restrict__ bh, const bf16* __restrict__ h_in,
    bf16* __restrict__ h_out, float* __restrict__ c,
    float* __restrict__ Q, int t) {
    __shared__ __align__(16) bf16 Hs[64 * 264];  // 256+8 pad per row
    __shared__ float Gs[4][64][17];              // activated gates, padded
    const int tid  = threadIdx.x;
    const int lane = tid & 63, g = tid >> 6;
    const int l15 = lane & 15, quad = lane >> 4;
    const int j0 = blockIdx.x * 16;
    const int wrow = g * HD_ + j0 + l15;  // row in WhT

    f32x4 acc[4];
    for (int mt = 0; mt < 4; ++mt) acc[mt] = f32x4{0.f, 0.f, 0.f, 0.f};

    for (int ks = 0; ks < 4; ++ks) {  // 256-wide K chunks
        for (int i = 0; i < 8; ++i) {
            const int L = tid + i * 256;
            const int r = L >> 5, s = L & 31;
            *reinterpret_cast<i32x4*>(&Hs[r * 264 + s * 8]) =
                *reinterpret_cast<const i32x4*>(h_in + (size_t)r * HD_ + ks * 256 + s * 8);
        }
        __syncthreads();
        bf16x8 bfv[8];  // preload 8 B-fragments -> loads pipeline in flight
        for (int kk = 0; kk < 8; ++kk)
            bfv[kk] = *reinterpret_cast<const bf16x8*>(
                whT + (size_t)wrow * HD_ + ks * 256 + kk * 32 + quad * 8);
        for (int kk = 0; kk < 8; ++kk) {
            for (int mt = 0; mt < 4; ++mt) {
                const bf16x8 a = *reinterpret_cast<const bf16x8*>(
                    &Hs[(mt * 16 + l15) * 264 + kk * 32 + quad * 8]);
                acc[mt] = __builtin_amdgcn_mfma_f32_16x16x32_bf16(
                    a, bfv[kk], acc[mt], 0, 0, 0);
            }
        }
        __syncthreads();
    }

    // activations into LDS
    const int col = g * HD_ + j0 + l15;
    const float bhv = bh[col];
    for (int mt = 0; mt < 4; ++mt) {
        for (int r = 0; r < 4; ++r) {
            const int b = mt * 16 + quad * 4 + r;
            const float pre = acc[mt][r] + bhv +
                __bfloat162float(gates[((size_t)(t * 64 + b)) * NG_ + col]);
            Gs[g][b][l15] = (g == 2) ? tanh_fast(pre) : sigmoid_fast(pre);
        }
    }
    __syncthreads();

    // fused cell update: 1024 (b, j) pairs, 4 per thread
    for (int i = 0; i < 4; ++i) {
        const int p = tid + i * 256;
        const int b = p >> 4, jl = p & 15;
        const float f = Gs[0][b][jl], in = Gs[1][b][jl];
        const float a = Gs[2][b][jl], o = Gs[3][b][jl];
        const int cidx = b * HD_ + j0 + jl;
        const float cn = f * c[cidx] + in * a;
        c[cidx] = cn;
        const float h = o * tanh_fast(cn);
        h_out[cidx] = __float2bfloat16(h);
        Q[((size_t)b * T_ + t) * HD_ + j0 + jl] = h;
    }
}

// ------------------------------------------------------------------ tail ----
__global__ __launch_bounds__(256) void tail_kernel(
    const float* __restrict__ c, float* __restrict__ out) {
    const int i = blockIdx.x * 256 + threadIdx.x;  // < 65536
    const int b = i >> 10, j = i & 1023;
    out[(size_t)M1_ * HD_ + i] = out[((size_t)b * T_ + 255) * HD_ + j];       // hT
    out[(size_t)M1_ * HD_ + B_ * HD_ + i] = c[i];                             // cT
}

// -------------------------------------------------------------- launcher ----
extern "C" void kernel_launch(void* const* d_in, const int* in_sizes, int n_in,
                              void* d_out, int out_size, void* d_ws, size_t ws_size,
                              hipStream_t stream) {
    const float* x  = (const float*)d_in[0];
    const float* Wi = (const float*)d_in[1];
    const float* bi = (const float*)d_in[2];
    const float* Wh = (const float*)d_in[3];
    const float* bh = (const float*)d_in[4];
    float* out = (float*)d_out;

    char* ws = (char*)d_ws;
    size_t off = 0;
    bf16* xb    = (bf16*)(ws + off); off += (size_t)M1_ * ID_ * 2;   // 16 MB
    bf16* wiT   = (bf16*)(ws + off); off += (size_t)NG_ * ID_ * 2;   // 4 MB
    bf16* whT   = (bf16*)(ws + off); off += (size_t)NG_ * HD_ * 2;   // 8 MB
    bf16* gates = (bf16*)(ws + off); off += (size_t)T_ * B_ * NG_ * 2; // 128 MB
    bf16* h0    = (bf16*)(ws + off); off += (size_t)B_ * HD_ * 2;
    bf16* h1    = (bf16*)(ws + off); off += (size_t)B_ * HD_ * 2;
    float* c    = (float*)(ws + off); off += (size_t)B_ * HD_ * 4;

    prep_kernel<<<8192, 256, 0, stream>>>(x, Wi, Wh, xb, wiT, whT, h0, c);
    gates_gemm_kernel<<<dim3(128, 32), 256, 0, stream>>>(xb, wiT, bi, gates);
    for (int t = 0; t < T_; ++t) {
        bf16* hin  = (t & 1) ? h1 : h0;
        bf16* hout = (t & 1) ? h0 : h1;
        lstm_step_kernel<<<64, 256, 0, stream>>>(gates, whT, bh, hin, hout, c,
                                                 out, t);
    }
    tail_kernel<<<256, 256, 0, stream>>>(c, out);
}

// Round 2
// 3934.567 us; speedup vs baseline: 1.0367x; 1.0367x over previous
//
#include <hip/hip_runtime.h>
#include <hip/hip_bf16.h>

// LSTM B=64, T=256, ID=512, HD=1024. Gates order F,I,A,O.
// prep            : x->bf16; Wi,Wh transposed+bf16; zero grid-barrier counter.
// gates_gemm      : gates2 = bf16(x@Wi + bi + bh), layout [T][128 blk][64 b][32 lcol],
//                   lcol = g*8 + jl (block = 8 hidden units, 4 gates).
// lstm_persistent : cooperative, 128 blocks x 256 thr, 1 block/CU. Wh slice in
//                   LDS (66 KB). Per step: stage h (2x64KB chunks) -> MFMA
//                   16x16x32 (4 m-tiles x 2 n-tiles, K=1024) -> activations ->
//                   cell update (c in regs) -> grid barrier.

#define B_  64
#define T_  256
#define ID_ 512
#define HD_ 1024
#define NG_ 4096
#define M1_ (B_ * T_)
#define NBLK 128
#define UPB  8            // hidden units per block
#define WH_STRIDE 1032    // 1024+8: 16B-aligned rows, 2-way bank alias (free)
#define HS_STRIDE 520     // 512+8

typedef __bf16 bf16x8 __attribute__((ext_vector_type(8)));
typedef float  f32x4  __attribute__((ext_vector_type(4)));
typedef int    i32x4  __attribute__((ext_vector_type(4)));
typedef short  s16x4  __attribute__((ext_vector_type(4)));

using bf16 = __hip_bfloat16;

__device__ __forceinline__ float sigmoid_fast(float x) {
    return 1.0f / (1.0f + __expf(-x));
}
__device__ __forceinline__ float tanh_fast(float x) {
    return 1.0f - 2.0f / (__expf(2.0f * x) + 1.0f);  // saturates correctly
}

// ---------------------------------------------------------------- prep ----
__global__ __launch_bounds__(256) void prep_kernel(
    const float* __restrict__ x, const float* __restrict__ Wi,
    const float* __restrict__ Wh, bf16* __restrict__ xb,
    bf16* __restrict__ wiT, bf16* __restrict__ whT, int* __restrict__ gcount) {
    const int tid = blockIdx.x * 256 + threadIdx.x;  // [0, 2097152)
    if (tid == 0) *gcount = 0;

    const float4 v = reinterpret_cast<const float4*>(x)[tid];
    bf16 tmp[4] = { __float2bfloat16(v.x), __float2bfloat16(v.y),
                    __float2bfloat16(v.z), __float2bfloat16(v.w) };
    *reinterpret_cast<s16x4*>(xb + 4 * (size_t)tid) =
        *reinterpret_cast<s16x4*>(tmp);

    {   // WiT[n][k] = Wi[k][n]
        const int n = tid >> 9, k = tid & 511;
        wiT[tid] = __float2bfloat16(Wi[(size_t)k * NG_ + n]);
    }
    for (int e = 0; e < 2; ++e) {  // WhT[n][k] = Wh[k][n]
        const int idx = 2 * tid + e;
        const int n = idx >> 10, k = idx & 1023;
        whT[idx] = __float2bfloat16(Wh[(size_t)k * NG_ + n]);
    }
}

// ---------------------------------------------------- phase-1 gates GEMM ----
__global__ __launch_bounds__(256) void gates_gemm_kernel(
    const bf16* __restrict__ xb, const bf16* __restrict__ wiT,
    const float* __restrict__ bi, const float* __restrict__ bh,
    bf16* __restrict__ gates2) {
    __shared__ __align__(16) bf16 As[128 * 40];
    __shared__ __align__(16) bf16 Bs[128 * 40];
    const int tid  = threadIdx.x;
    const int lane = tid & 63, wave = tid >> 6;
    const int wm = wave >> 1, wn = wave & 1;
    const int l15 = lane & 15, quad = lane >> 4;
    const int row0 = blockIdx.x * 128, col0 = blockIdx.y * 128;

    f32x4 acc[4][4];
    for (int i = 0; i < 4; ++i)
        for (int j = 0; j < 4; ++j) acc[i][j] = f32x4{0.f, 0.f, 0.f, 0.f};

    for (int kt = 0; kt < ID_ / 32; ++kt) {
        const int k0 = kt * 32;
        for (int L = tid; L < 512; L += 256) {
            const int r = L >> 2, s = L & 3;
            *reinterpret_cast<i32x4*>(&As[r * 40 + s * 8]) =
                *reinterpret_cast<const i32x4*>(xb + (size_t)(row0 + r) * ID_ + k0 + s * 8);
            *reinterpret_cast<i32x4*>(&Bs[r * 40 + s * 8]) =
                *reinterpret_cast<const i32x4*>(wiT + (size_t)(col0 + r) * ID_ + k0 + s * 8);
        }
        __syncthreads();
        bf16x8 af[4], bfv[4];
        for (int mt = 0; mt < 4; ++mt)
            af[mt] = *reinterpret_cast<const bf16x8*>(
                &As[(wm * 64 + mt * 16 + l15) * 40 + quad * 8]);
        for (int nt = 0; nt < 4; ++nt)
            bfv[nt] = *reinterpret_cast<const bf16x8*>(
                &Bs[(wn * 64 + nt * 16 + l15) * 40 + quad * 8]);
        for (int mt = 0; mt < 4; ++mt)
            for (int nt = 0; nt < 4; ++nt)
                acc[mt][nt] = __builtin_amdgcn_mfma_f32_16x16x32_bf16(
                    af[mt], bfv[nt], acc[mt][nt], 0, 0, 0);
        __syncthreads();
    }
    // epilogue: + (bi+bh), store permuted to [T][blk][b][lcol]
    for (int mt = 0; mt < 4; ++mt) {
        for (int nt = 0; nt < 4; ++nt) {
            const int cg = col0 + wn * 64 + nt * 16 + l15;
            const int g = cg >> 10, u = cg & 1023;
            const int blk = u >> 3, jl = u & 7, lcol = g * 8 + jl;
            const float bias = bi[cg] + bh[cg];
            for (int r = 0; r < 4; ++r) {
                const int rg = row0 + wm * 64 + mt * 16 + quad * 4 + r;
                const int b = rg >> 8, t = rg & 255;  // row = b*T + t
                gates2[(((size_t)t * NBLK + blk) * B_ + b) * 32 + lcol] =
                    __float2bfloat16(acc[mt][nt][r] + bias);
            }
        }
    }
}

// ---------------------------------------------------------- grid barrier ----
__device__ __forceinline__ void grid_barrier(int* cnt, int idx) {
    __syncthreads();
    if (threadIdx.x == 0) {
        // release: publishes this block's h stores (cache ops are physical,
        // so the whole XCD L2 writeback covers all waves' stores)
        __hip_atomic_fetch_add(cnt, 1, __ATOMIC_RELEASE, __HIP_MEMORY_SCOPE_AGENT);
        const int target = NBLK * (idx + 1);
        while (__hip_atomic_load(cnt, __ATOMIC_RELAXED, __HIP_MEMORY_SCOPE_AGENT) < target)
            __builtin_amdgcn_s_sleep(1);
    }
    __syncthreads();
    // acquire once (not per spin iter): invalidate stale L1/L2 lines of h
    __builtin_amdgcn_fence(__ATOMIC_ACQUIRE, "agent");
    __syncthreads();
}

// ------------------------------------------------- persistent LSTM steps ----
__global__ __launch_bounds__(256) void lstm_persistent_kernel(
    const bf16* __restrict__ gates2, const bf16* __restrict__ whT,
    bf16* __restrict__ hbuf, float* __restrict__ out, int* __restrict__ gcount) {
    __shared__ __align__(16) bf16 Whs[32 * WH_STRIDE];  // 66,048 B
    __shared__ __align__(16) bf16 Hs[64 * HS_STRIDE];   // 66,560 B
    __shared__ __align__(16) bf16 Gx[64 * 32];          //  4,096 B
    __shared__ float Gs[64][36];                        //  9,216 B

    const int tid  = threadIdx.x;
    const int lane = tid & 63, w = tid >> 6;
    const int l15 = lane & 15, quad = lane >> 4;
    const int blk = blockIdx.x;                 // hidden units [blk*8, blk*8+8)

    // Wh slice -> LDS: LDS row lcol=g*8+jl  <-  whT row g*1024 + blk*8 + jl
    for (int i = tid; i < 32 * 128; i += 256) {
        const int r = i >> 7, s = i & 127;
        const int gr = (r >> 3) * HD_ + blk * UPB + (r & 7);
        *reinterpret_cast<i32x4*>(&Whs[r * WH_STRIDE + s * 8]) =
            *reinterpret_cast<const i32x4*>(whT + (size_t)gr * HD_ + s * 8);
    }
    // zero h ping buffer
    for (int i = blk * 256 + tid; i < B_ * HD_ / 4; i += NBLK * 256)
        *reinterpret_cast<s16x4*>(hbuf + (size_t)i * 4) = s16x4{0, 0, 0, 0};

    float creg[2] = {0.f, 0.f};

    grid_barrier(gcount, 0);   // h0 visible everywhere; Whs covered by syncthreads

    for (int t = 0; t < T_; ++t) {
        const bf16* hin  = hbuf + (size_t)(t & 1) * (B_ * HD_);
        bf16*       hout = hbuf + (size_t)((t + 1) & 1) * (B_ * HD_);

        // stage this block's gate row (4 KB, coalesced) + h chunk 0
        *reinterpret_cast<i32x4*>(&Gx[tid * 8]) =
            *reinterpret_cast<const i32x4*>(
                gates2 + ((size_t)t * NBLK + blk) * (B_ * 32) + tid * 8);
        for (int i = 0; i < 16; ++i) {
            const int L = tid + i * 256;
            const int r = L >> 6, s = L & 63;
            *reinterpret_cast<i32x4*>(&Hs[r * HS_STRIDE + s * 8]) =
                *reinterpret_cast<const i32x4*>(hin + (size_t)r * HD_ + s * 8);
        }
        __syncthreads();

        f32x4 acc[2][2];
        for (int nt = 0; nt < 2; ++nt)
            for (int p = 0; p < 2; ++p) acc[nt][p] = f32x4{0.f, 0.f, 0.f, 0.f};

        for (int kk = 0; kk < 16; ++kk) {  // chunk 0: k in [0,512)
            const bf16x8 a = *reinterpret_cast<const bf16x8*>(
                &Hs[(w * 16 + l15) * HS_STRIDE + kk * 32 + quad * 8]);
#pragma unroll
            for (int nt = 0; nt < 2; ++nt) {
                const bf16x8 b = *reinterpret_cast<const bf16x8*>(
                    &Whs[(nt * 16 + l15) * WH_STRIDE + kk * 32 + quad * 8]);
                acc[nt][kk & 1] = __builtin_amdgcn_mfma_f32_16x16x32_bf16(
                    a, b, acc[nt][kk & 1], 0, 0, 0);
            }
        }
        __syncthreads();
        for (int i = 0; i < 16; ++i) {     // stage h chunk 1
            const int L = tid + i * 256;
            const int r = L >> 6, s = L & 63;
            *reinterpret_cast<i32x4*>(&Hs[r * HS_STRIDE + s * 8]) =
                *reinterpret_cast<const i32x4*>(hin + (size_t)r * HD_ + 512 + s * 8);
        }
        __syncthreads();
        for (int kk = 0; kk < 16; ++kk) {  // chunk 1: k in [512,1024)
            const bf16x8 a = *reinterpret_cast<const bf16x8*>(
                &Hs[(w * 16 + l15) * HS_STRIDE + kk * 32 + quad * 8]);
#pragma unroll
            for (int nt = 0; nt < 2; ++nt) {
                const bf16x8 b = *reinterpret_cast<const bf16x8*>(
                    &Whs[(nt * 16 + l15) * WH_STRIDE + 512 + kk * 32 + quad * 8]);
                acc[nt][kk & 1] = __builtin_amdgcn_mfma_f32_16x16x32_bf16(
                    a, b, acc[nt][kk & 1], 0, 0, 0);
            }
        }

        // activations -> Gs
#pragma unroll
        for (int nt = 0; nt < 2; ++nt) {
            const int lcol = nt * 16 + l15;
            const int g = lcol >> 3;
#pragma unroll
            for (int r2 = 0; r2 < 4; ++r2) {
                const int b = w * 16 + quad * 4 + r2;
                const float pre = acc[nt][0][r2] + acc[nt][1][r2] +
                                  __bfloat162float(Gx[b * 32 + lcol]);
                Gs[b][lcol] = (g == 2) ? tanh_fast(pre) : sigmoid_fast(pre);
            }
        }
        __syncthreads();

        // cell update: thread owns cells (b = p>>3, jl = p&7), c in registers
#pragma unroll
        for (int i = 0; i < 2; ++i) {
            const int p = tid + i * 256;
            const int b = p >> 3, jl = p & 7;
            const float f  = Gs[b][jl],      in = Gs[b][8 + jl];
            const float a  = Gs[b][16 + jl], o  = Gs[b][24 + jl];
            const float cn = f * creg[i] + in * a;
            creg[i] = cn;
            const float h = o * tanh_fast(cn);
            const int hidx = b * HD_ + blk * UPB + jl;
            hout[hidx] = __float2bfloat16(h);
            out[((size_t)b * T_ + t) * HD_ + blk * UPB + jl] = h;
            if (t == T_ - 1) {
                out[(size_t)M1_ * HD_ + hidx] = h;                 // hT
                out[(size_t)M1_ * HD_ + B_ * HD_ + hidx] = cn;     // cT
            }
        }
        grid_barrier(gcount, t + 1);
    }
}

// -------------------------------------------------------------- launcher ----
extern "C" void kernel_launch(void* const* d_in, const int* in_sizes, int n_in,
                              void* d_out, int out_size, void* d_ws, size_t ws_size,
                              hipStream_t stream) {
    const float* x  = (const float*)d_in[0];
    const float* Wi = (const float*)d_in[1];
    const float* bi = (const float*)d_in[2];
    const float* Wh = (const float*)d_in[3];
    const float* bh = (const float*)d_in[4];
    float* out = (float*)d_out;

    char* ws = (char*)d_ws;
    size_t off = 0;
    bf16* xb     = (bf16*)(ws + off); off += (size_t)M1_ * ID_ * 2;       // 16 MB
    bf16* wiT    = (bf16*)(ws + off); off += (size_t)NG_ * ID_ * 2;       // 4 MB
    bf16* whT    = (bf16*)(ws + off); off += (size_t)NG_ * HD_ * 2;       // 8 MB
    bf16* gates2 = (bf16*)(ws + off); off += (size_t)T_ * B_ * NG_ * 2;   // 128 MB
    bf16* hbuf   = (bf16*)(ws + off); off += (size_t)2 * B_ * HD_ * 2;    // 256 KB
    int* gcount  = (int*)(ws + off);  off += 256;

    prep_kernel<<<8192, 256, 0, stream>>>(x, Wi, Wh, xb, wiT, whT, gcount);
    gates_gemm_kernel<<<dim3(128, 32), 256, 0, stream>>>(xb, wiT, bi, bh, gates2);

    void* args[] = {(void*)&gates2, (void*)&whT, (void*)&hbuf, (void*)&out,
                    (void*)&gcount};
    hipLaunchCooperativeKernel((void*)lstm_persistent_kernel, dim3(NBLK),
                               dim3(256), args, 0, stream);
}

// Round 3
// 3607.620 us; speedup vs baseline: 1.1307x; 1.0906x over previous
//
#include <hip/hip_runtime.h>
#include <hip/hip_bf16.h>

// LSTM B=64, T=256, ID=512, HD=1024. Gates order F,I,A,O.
// Round 3: fence-free cross-XCD h exchange. h goes through MALL via volatile
// (sc0/sc1) loads/stores; per-step arrival counters with RELAXED agent atomics
// (no L2 writeback/invalidate ops). Double buffer safe: counter[t] incremented
// only after block finished reading h[t-1] and writing h[t].

#define B_  64
#define T_  256
#define ID_ 512
#define HD_ 1024
#define NG_ 4096
#define M1_ (B_ * T_)
#define NBLK 128
#define UPB  8            // hidden units per block
#define WH_STRIDE 1032    // 1024+8
#define HS_STRIDE 520     // 512+8
#define CNT_STRIDE 16     // ints; one 64B line per step counter

typedef __bf16 bf16x8 __attribute__((ext_vector_type(8)));
typedef float  f32x4  __attribute__((ext_vector_type(4)));
typedef int    i32x4  __attribute__((ext_vector_type(4)));
typedef short  s16x4  __attribute__((ext_vector_type(4)));

using bf16 = __hip_bfloat16;

__device__ __forceinline__ float sigmoid_fast(float x) {
    return 1.0f / (1.0f + __expf(-x));
}
__device__ __forceinline__ float tanh_fast(float x) {
    return 1.0f - 2.0f / (__expf(2.0f * x) + 1.0f);
}
__device__ __forceinline__ unsigned short bf16_bits(float x) {
    union { bf16 h; unsigned short u; } cv;
    cv.h = __float2bfloat16(x);
    return cv.u;
}

// ---------------------------------------------------------------- prep ----
__global__ __launch_bounds__(256) void prep_kernel(
    const float* __restrict__ x, const float* __restrict__ Wi,
    const float* __restrict__ Wh, bf16* __restrict__ xb,
    bf16* __restrict__ wiT, bf16* __restrict__ whT,
    bf16* __restrict__ hbuf, int* __restrict__ cnt) {
    const int tid = blockIdx.x * 256 + threadIdx.x;  // [0, 2097152)

    // zero step counters (T_*CNT_STRIDE ints = 16 KB)
    if (tid < T_ * CNT_STRIDE) cnt[tid] = 0;
    // zero h ping buffer 0 (h[-1] = 0): 64K bf16 via 32768 x s16x4
    if (tid < (B_ * HD_) / 4)
        *reinterpret_cast<s16x4*>(hbuf + (size_t)tid * 4) = s16x4{0, 0, 0, 0};

    const float4 v = reinterpret_cast<const float4*>(x)[tid];
    bf16 tmp[4] = { __float2bfloat16(v.x), __float2bfloat16(v.y),
                    __float2bfloat16(v.z), __float2bfloat16(v.w) };
    *reinterpret_cast<s16x4*>(xb + 4 * (size_t)tid) =
        *reinterpret_cast<s16x4*>(tmp);

    {   // WiT[n][k] = Wi[k][n]
        const int n = tid >> 9, k = tid & 511;
        wiT[tid] = __float2bfloat16(Wi[(size_t)k * NG_ + n]);
    }
    for (int e = 0; e < 2; ++e) {  // WhT[n][k] = Wh[k][n]
        const int idx = 2 * tid + e;
        const int n = idx >> 10, k = idx & 1023;
        whT[idx] = __float2bfloat16(Wh[(size_t)k * NG_ + n]);
    }
}

// ---------------------------------------------------- phase-1 gates GEMM ----
__global__ __launch_bounds__(256) void gates_gemm_kernel(
    const bf16* __restrict__ xb, const bf16* __restrict__ wiT,
    const float* __restrict__ bi, const float* __restrict__ bh,
    bf16* __restrict__ gates2) {
    __shared__ __align__(16) bf16 As[128 * 40];
    __shared__ __align__(16) bf16 Bs[128 * 40];
    const int tid  = threadIdx.x;
    const int lane = tid & 63, wave = tid >> 6;
    const int wm = wave >> 1, wn = wave & 1;
    const int l15 = lane & 15, quad = lane >> 4;
    const int row0 = blockIdx.x * 128, col0 = blockIdx.y * 128;

    f32x4 acc[4][4];
    for (int i = 0; i < 4; ++i)
        for (int j = 0; j < 4; ++j) acc[i][j] = f32x4{0.f, 0.f, 0.f, 0.f};

    for (int kt = 0; kt < ID_ / 32; ++kt) {
        const int k0 = kt * 32;
        for (int L = tid; L < 512; L += 256) {
            const int r = L >> 2, s = L & 3;
            *reinterpret_cast<i32x4*>(&As[r * 40 + s * 8]) =
                *reinterpret_cast<const i32x4*>(xb + (size_t)(row0 + r) * ID_ + k0 + s * 8);
            *reinterpret_cast<i32x4*>(&Bs[r * 40 + s * 8]) =
                *reinterpret_cast<const i32x4*>(wiT + (size_t)(col0 + r) * ID_ + k0 + s * 8);
        }
        __syncthreads();
        bf16x8 af[4], bfv[4];
        for (int mt = 0; mt < 4; ++mt)
            af[mt] = *reinterpret_cast<const bf16x8*>(
                &As[(wm * 64 + mt * 16 + l15) * 40 + quad * 8]);
        for (int nt = 0; nt < 4; ++nt)
            bfv[nt] = *reinterpret_cast<const bf16x8*>(
                &Bs[(wn * 64 + nt * 16 + l15) * 40 + quad * 8]);
        for (int mt = 0; mt < 4; ++mt)
            for (int nt = 0; nt < 4; ++nt)
                acc[mt][nt] = __builtin_amdgcn_mfma_f32_16x16x32_bf16(
                    af[mt], bfv[nt], acc[mt][nt], 0, 0, 0);
        __syncthreads();
    }
    // epilogue: + (bi+bh), store permuted to [T][blk][b][lcol]
    for (int mt = 0; mt < 4; ++mt) {
        for (int nt = 0; nt < 4; ++nt) {
            const int cg = col0 + wn * 64 + nt * 16 + l15;
            const int g = cg >> 10, u = cg & 1023;
            const int blk = u >> 3, jl = u & 7, lcol = g * 8 + jl;
            const float bias = bi[cg] + bh[cg];
            for (int r = 0; r < 4; ++r) {
                const int rg = row0 + wm * 64 + mt * 16 + quad * 4 + r;
                const int b = rg >> 8, t = rg & 255;  // row = b*T + t
                gates2[(((size_t)t * NBLK + blk) * B_ + b) * 32 + lcol] =
                    __float2bfloat16(acc[mt][nt][r] + bias);
            }
        }
    }
}

// ------------------------------------------------- persistent LSTM steps ----
__global__ __launch_bounds__(256) void lstm_persistent_kernel(
    const bf16* __restrict__ gates2, const bf16* __restrict__ whT,
    bf16* __restrict__ hbuf, float* __restrict__ out, int* __restrict__ cnt) {
    __shared__ __align__(16) bf16 Whs[32 * WH_STRIDE];  // 66,048 B
    __shared__ __align__(16) bf16 Hs[64 * HS_STRIDE];   // 66,560 B
    __shared__ __align__(16) bf16 Gx[64 * 32];          //  4,096 B
    __shared__ float Gs[64][36];                        //  9,216 B

    const int tid  = threadIdx.x;
    const int lane = tid & 63, w = tid >> 6;
    const int l15 = lane & 15, quad = lane >> 4;
    const int blk = blockIdx.x;                 // hidden units [blk*8, blk*8+8)

    // Wh slice -> LDS (row lcol=g*8+jl  <-  whT row g*1024 + blk*8 + jl)
    for (int i = tid; i < 32 * 128; i += 256) {
        const int r = i >> 7, s = i & 127;
        const int gr = (r >> 3) * HD_ + blk * UPB + (r & 7);
        *reinterpret_cast<i32x4*>(&Whs[r * WH_STRIDE + s * 8]) =
            *reinterpret_cast<const i32x4*>(whT + (size_t)gr * HD_ + s * 8);
    }

    // cell-update thread mapping: thread owns (b = tid>>2, units 2jp, 2jp+1)
    const int cb = tid >> 2, jp = tid & 3, u0 = jp << 1;
    float c0 = 0.f, c1 = 0.f;

    for (int t = 0; t < T_; ++t) {
        const bf16* hin  = hbuf + (size_t)(t & 1) * (B_ * HD_);
        bf16*       hout = hbuf + (size_t)((t + 1) & 1) * (B_ * HD_);

        // wait for h[t-1] to be fully published (fence-free: relaxed poll)
        if (t > 0 && tid == 0) {
            while (__hip_atomic_load(&cnt[(t - 1) * CNT_STRIDE],
                                     __ATOMIC_RELAXED,
                                     __HIP_MEMORY_SCOPE_AGENT) < NBLK)
                __builtin_amdgcn_s_sleep(1);
        }
        __syncthreads();

        // stage gate row (4 KB coalesced, plain) + h chunk 0 (volatile: MALL)
        *reinterpret_cast<i32x4*>(&Gx[tid * 8]) =
            *reinterpret_cast<const i32x4*>(
                gates2 + ((size_t)t * NBLK + blk) * (B_ * 32) + tid * 8);
        for (int i = 0; i < 16; ++i) {
            const int L = tid + i * 256;
            const int r = L >> 6, s = L & 63;
            const i32x4 hv = *reinterpret_cast<const volatile i32x4*>(
                hin + (size_t)r * HD_ + s * 8);
            *reinterpret_cast<i32x4*>(&Hs[r * HS_STRIDE + s * 8]) = hv;
        }
        __syncthreads();

        f32x4 acc[2][2];
        for (int nt = 0; nt < 2; ++nt)
            for (int p = 0; p < 2; ++p) acc[nt][p] = f32x4{0.f, 0.f, 0.f, 0.f};

        for (int kk = 0; kk < 16; ++kk) {  // chunk 0: k in [0,512)
            const bf16x8 a = *reinterpret_cast<const bf16x8*>(
                &Hs[(w * 16 + l15) * HS_STRIDE + kk * 32 + quad * 8]);
#pragma unroll
            for (int nt = 0; nt < 2; ++nt) {
                const bf16x8 b = *reinterpret_cast<const bf16x8*>(
                    &Whs[(nt * 16 + l15) * WH_STRIDE + kk * 32 + quad * 8]);
                acc[nt][kk & 1] = __builtin_amdgcn_mfma_f32_16x16x32_bf16(
                    a, b, acc[nt][kk & 1], 0, 0, 0);
            }
        }
        __syncthreads();
        for (int i = 0; i < 16; ++i) {     // stage h chunk 1 (volatile)
            const int L = tid + i * 256;
            const int r = L >> 6, s = L & 63;
            const i32x4 hv = *reinterpret_cast<const volatile i32x4*>(
                hin + (size_t)r * HD_ + 512 + s * 8);
            *reinterpret_cast<i32x4*>(&Hs[r * HS_STRIDE + s * 8]) = hv;
        }
        __syncthreads();
        for (int kk = 0; kk < 16; ++kk) {  // chunk 1: k in [512,1024)
            const bf16x8 a = *reinterpret_cast<const bf16x8*>(
                &Hs[(w * 16 + l15) * HS_STRIDE + kk * 32 + quad * 8]);
#pragma unroll
            for (int nt = 0; nt < 2; ++nt) {
                const bf16x8 b = *reinterpret_cast<const bf16x8*>(
                    &Whs[(nt * 16 + l15) * WH_STRIDE + 512 + kk * 32 + quad * 8]);
                acc[nt][kk & 1] = __builtin_amdgcn_mfma_f32_16x16x32_bf16(
                    a, b, acc[nt][kk & 1], 0, 0, 0);
            }
        }

        // activations -> Gs
#pragma unroll
        for (int nt = 0; nt < 2; ++nt) {
            const int lcol = nt * 16 + l15;
            const int g = lcol >> 3;
#pragma unroll
            for (int r2 = 0; r2 < 4; ++r2) {
                const int b = w * 16 + quad * 4 + r2;
                const float pre = acc[nt][0][r2] + acc[nt][1][r2] +
                                  __bfloat162float(Gx[b * 32 + lcol]);
                Gs[b][lcol] = (g == 2) ? tanh_fast(pre) : sigmoid_fast(pre);
            }
        }
        __syncthreads();

        // cell update: 2 adjacent units per thread; h published via volatile
        {
            const float f0 = Gs[cb][u0],      i0 = Gs[cb][8 + u0];
            const float a0 = Gs[cb][16 + u0], o0 = Gs[cb][24 + u0];
            const float f1 = Gs[cb][u0 + 1],      i1 = Gs[cb][8 + u0 + 1];
            const float a1 = Gs[cb][16 + u0 + 1], o1 = Gs[cb][24 + u0 + 1];
            const float cn0 = f0 * c0 + i0 * a0;  c0 = cn0;
            const float cn1 = f1 * c1 + i1 * a1;  c1 = cn1;
            const float h0 = o0 * tanh_fast(cn0);
            const float h1 = o1 * tanh_fast(cn1);
            const int hidx = cb * HD_ + blk * UPB + u0;
            const unsigned int packed =
                (unsigned int)bf16_bits(h0) | ((unsigned int)bf16_bits(h1) << 16);
            *reinterpret_cast<volatile unsigned int*>(hout + hidx) = packed;
            float2 ho = make_float2(h0, h1);
            *reinterpret_cast<float2*>(
                out + ((size_t)cb * T_ + t) * HD_ + blk * UPB + u0) = ho;
            if (t == T_ - 1) {
                *reinterpret_cast<float2*>(out + (size_t)M1_ * HD_ + hidx) = ho;
                *reinterpret_cast<float2*>(
                    out + (size_t)M1_ * HD_ + B_ * HD_ + hidx) =
                    make_float2(cn0, cn1);
            }
        }
        // publish: syncthreads drains vmcnt (h stores at MALL), then counter
        __syncthreads();
        if (tid == 0)
            __hip_atomic_fetch_add(&cnt[t * CNT_STRIDE], 1, __ATOMIC_RELAXED,
                                   __HIP_MEMORY_SCOPE_AGENT);
    }
}

// -------------------------------------------------------------- launcher ----
extern "C" void kernel_launch(void* const* d_in, const int* in_sizes, int n_in,
                              void* d_out, int out_size, void* d_ws, size_t ws_size,
                              hipStream_t stream) {
    const float* x  = (const float*)d_in[0];
    const float* Wi = (const float*)d_in[1];
    const float* bi = (const float*)d_in[2];
    const float* Wh = (const float*)d_in[3];
    const float* bh = (const float*)d_in[4];
    float* out = (float*)d_out;

    char* ws = (char*)d_ws;
    size_t off = 0;
    bf16* xb     = (bf16*)(ws + off); off += (size_t)M1_ * ID_ * 2;       // 16 MB
    bf16* wiT    = (bf16*)(ws + off); off += (size_t)NG_ * ID_ * 2;       // 4 MB
    bf16* whT    = (bf16*)(ws + off); off += (size_t)NG_ * HD_ * 2;       // 8 MB
    bf16* gates2 = (bf16*)(ws + off); off += (size_t)T_ * B_ * NG_ * 2;   // 128 MB
    bf16* hbuf   = (bf16*)(ws + off); off += (size_t)2 * B_ * HD_ * 2;    // 256 KB
    int* cnt     = (int*)(ws + off);  off += (size_t)T_ * CNT_STRIDE * 4; // 16 KB

    prep_kernel<<<8192, 256, 0, stream>>>(x, Wi, Wh, xb, wiT, whT, hbuf, cnt);
    gates_gemm_kernel<<<dim3(128, 32), 256, 0, stream>>>(xb, wiT, bi, bh, gates2);

    void* args[] = {(void*)&gates2, (void*)&whT, (void*)&hbuf, (void*)&out,
                    (void*)&cnt};
    hipLaunchCooperativeKernel((void*)lstm_persistent_kernel, dim3(NBLK),
                               dim3(256), args, 0, stream);
}

// Round 5
// 2980.961 us; speedup vs baseline: 1.3684x; 1.2102x over previous
//
#include <hip/hip_runtime.h>
#include <hip/hip_bf16.h>

// LSTM B=64, T=256, ID=512, HD=1024. Gates F,I,A,O.
// Round 5: LDS-free wave-decoupled persistent recurrence, PLAIN launch.
//  - D = Wh x h^T: A-operand = Wh slice in 256 VGPRs (step-invariant),
//    B-operand = h fragments loaded DIRECTLY from global (volatile -> MALL);
//    per-wave B-frags have zero duplication, so LDS staging was pure overhead.
//  - Per-(block,wave) flag lines, plain volatile stores/loads, no atomics,
//    no __syncthreads anywhere in the t-loop, no cooperative API.

#define B_  64
#define T_  256
#define ID_ 512
#define HD_ 1024
#define NG_ 4096
#define M1_ (B_ * T_)
#define NBLK 128
#define UPB  8

typedef __bf16 bf16x8 __attribute__((ext_vector_type(8)));
typedef float  f32x4  __attribute__((ext_vector_type(4)));
typedef int    i32x4  __attribute__((ext_vector_type(4)));
typedef short  s16x4  __attribute__((ext_vector_type(4)));

using bf16 = __hip_bfloat16;

__device__ __forceinline__ float sigmoid_fast(float x) {
    return 1.0f / (1.0f + __expf(-x));
}
__device__ __forceinline__ float tanh_fast(float x) {
    return 1.0f - 2.0f / (__expf(2.0f * x) + 1.0f);
}
__device__ __forceinline__ unsigned short bf16_bits(float x) {
    union { bf16 h; unsigned short u; } cv;
    cv.h = __float2bfloat16(x);
    return cv.u;
}
__device__ __forceinline__ bf16x8 vload8(const bf16* p) {
    union { i32x4 i; bf16x8 h; } cv;
    cv.i = *reinterpret_cast<const volatile i32x4*>(p);
    return cv.h;
}

// ---------------------------------------------------------------- prep ----
__global__ __launch_bounds__(256) void prep_kernel(
    const float* __restrict__ x, const float* __restrict__ Wi,
    const float* __restrict__ Wh, bf16* __restrict__ xb,
    bf16* __restrict__ wiT, bf16* __restrict__ whT,
    bf16* __restrict__ hbuf, int* __restrict__ flags) {
    const int tid = blockIdx.x * 256 + threadIdx.x;  // [0, 2097152)

    if (tid < NBLK * 4 * 16) flags[tid] = 0;          // 512 flag lines
    if (tid < (B_ * HD_) / 4)                         // h[-1] = 0 (buf0)
        *reinterpret_cast<s16x4*>(hbuf + (size_t)tid * 4) = s16x4{0, 0, 0, 0};

    const float4 v = reinterpret_cast<const float4*>(x)[tid];
    bf16 tmp[4] = { __float2bfloat16(v.x), __float2bfloat16(v.y),
                    __float2bfloat16(v.z), __float2bfloat16(v.w) };
    *reinterpret_cast<s16x4*>(xb + 4 * (size_t)tid) =
        *reinterpret_cast<s16x4*>(tmp);

    {   // WiT[n][k] = Wi[k][n]
        const int n = tid >> 9, k = tid & 511;
        wiT[tid] = __float2bfloat16(Wi[(size_t)k * NG_ + n]);
    }
    for (int e = 0; e < 2; ++e) {  // WhT[n][k] = Wh[k][n]
        const int idx = 2 * tid + e;
        const int n = idx >> 10, k = idx & 1023;
        whT[idx] = __float2bfloat16(Wh[(size_t)k * NG_ + n]);
    }
}

// ---------------------------------------------------- phase-1 gates GEMM ----
// gates3 layout: [t][blk][tid(256)][8] bf16, e = nt*4+r in step-MFMA acc order.
__global__ __launch_bounds__(256) void gates_gemm_kernel(
    const bf16* __restrict__ xb, const bf16* __restrict__ wiT,
    const float* __restrict__ bi, const float* __restrict__ bh,
    bf16* __restrict__ gates3) {
    __shared__ __align__(16) bf16 As[128 * 40];
    __shared__ __align__(16) bf16 Bs[128 * 40];
    const int tid  = threadIdx.x;
    const int lane = tid & 63, wave = tid >> 6;
    const int wm = wave >> 1, wn = wave & 1;
    const int l15 = lane & 15, quad = lane >> 4;
    const int row0 = blockIdx.x * 128, col0 = blockIdx.y * 128;

    f32x4 acc[4][4];
    for (int i = 0; i < 4; ++i)
        for (int j = 0; j < 4; ++j) acc[i][j] = f32x4{0.f, 0.f, 0.f, 0.f};

    for (int kt = 0; kt < ID_ / 32; ++kt) {
        const int k0 = kt * 32;
        for (int L = tid; L < 512; L += 256) {
            const int r = L >> 2, s = L & 3;
            *reinterpret_cast<i32x4*>(&As[r * 40 + s * 8]) =
                *reinterpret_cast<const i32x4*>(xb + (size_t)(row0 + r) * ID_ + k0 + s * 8);
            *reinterpret_cast<i32x4*>(&Bs[r * 40 + s * 8]) =
                *reinterpret_cast<const i32x4*>(wiT + (size_t)(col0 + r) * ID_ + k0 + s * 8);
        }
        __syncthreads();
        bf16x8 af[4], bfv[4];
        for (int mt = 0; mt < 4; ++mt)
            af[mt] = *reinterpret_cast<const bf16x8*>(
                &As[(wm * 64 + mt * 16 + l15) * 40 + quad * 8]);
        for (int nt = 0; nt < 4; ++nt)
            bfv[nt] = *reinterpret_cast<const bf16x8*>(
                &Bs[(wn * 64 + nt * 16 + l15) * 40 + quad * 8]);
        for (int mt = 0; mt < 4; ++mt)
            for (int nt = 0; nt < 4; ++nt)
                acc[mt][nt] = __builtin_amdgcn_mfma_f32_16x16x32_bf16(
                    af[mt], bfv[nt], acc[mt][nt], 0, 0, 0);
        __syncthreads();
    }
    // epilogue: +(bi+bh), store to gates3 in persistent-kernel acc order
    for (int mt = 0; mt < 4; ++mt) {
        for (int nt = 0; nt < 4; ++nt) {
            const int cg = col0 + wn * 64 + nt * 16 + l15;
            const int g = cg >> 10, u = cg & 1023;
            const int blk = u >> 3, jl = u & 7;
            const int lcol = g * 8 + jl;               // m-index in step MFMA
            const int nt2 = lcol >> 4, q2 = (lcol >> 2) & 3, r2 = lcol & 3;
            const int e = nt2 * 4 + r2;
            const float bias = bi[cg] + bh[cg];
            for (int r = 0; r < 4; ++r) {
                const int rg = row0 + wm * 64 + mt * 16 + quad * 4 + r;
                const int b = rg >> 8, t = rg & 255;   // row = b*T + t
                const int tid2 = (b >> 4) * 64 + q2 * 16 + (b & 15);
                gates3[(((size_t)t * NBLK + blk) * 256 + tid2) * 8 + e] =
                    __float2bfloat16(acc[mt][nt][r] + bias);
            }
        }
    }
}

// ------------------------------------------------- persistent LSTM steps ----
__global__ __launch_bounds__(256, 1) void lstm_persistent_kernel(
    const bf16* __restrict__ gates3, const bf16* __restrict__ whT,
    bf16* __restrict__ hbuf, float* __restrict__ out, int* __restrict__ flags) {
    const int tid  = threadIdx.x;
    const int lane = tid & 63, w = tid >> 6;
    const int l15 = lane & 15, quad = lane >> 4;
    const int blk = blockIdx.x;                 // hidden units [blk*8, blk*8+8)

    // ---- preload Wh A-fragments (step-invariant, 256 VGPRs) ----
    // A[m=lcol][k]: lcol = nt*16 + l15 -> whT row (lcol>>3)*HD + blk*8 + (lcol&7)
    bf16x8 awh[2][32];
#pragma unroll
    for (int nt = 0; nt < 2; ++nt) {
        const int lcol = nt * 16 + l15;
        const size_t wrow = (size_t)((lcol >> 3) * HD_ + blk * UPB + (lcol & 7));
#pragma unroll
        for (int kk = 0; kk < 32; ++kk)
            awh[nt][kk] = *reinterpret_cast<const bf16x8*>(
                whT + wrow * HD_ + kk * 32 + quad * 8);
    }

    // cell-update map (after shfl_xor(32) pairing quad<->quad^2):
    // thread covers (b = w*16+l15, units jl0, jl0+1)
    const int jl0 = 4 * (quad & 1) + 2 * (quad >> 1);
    const int b = w * 16 + l15;
    float c0 = 0.f, c1 = 0.f;

    // poll map: lane covers flag lines for blocks lane and lane+64, own wave
    volatile int* pf1 = (volatile int*)(flags + ((lane * 4 + w) << 4));
    volatile int* pf2 = (volatile int*)(flags + (((64 + lane) * 4 + w) << 4));
    volatile int* myflag = (volatile int*)(flags + ((blk * 4 + w) << 4));

    for (int t = 0; t < T_; ++t) {
        const bf16* hin  = hbuf + (size_t)(t & 1) * (B_ * HD_);
        bf16*       hout = hbuf + (size_t)((t + 1) & 1) * (B_ * HD_);

        // issue gates_x load early (plain, L2)
        const bf16x8 gx = *reinterpret_cast<const bf16x8*>(
            gates3 + (((size_t)t * NBLK + blk) * 256 + tid) * 8);

        // wait until all blocks' wave w published h[t-1]
        if (t > 0) {
            while (*pf1 < t) __builtin_amdgcn_s_sleep(1);
            while (*pf2 < t) __builtin_amdgcn_s_sleep(1);
        }

        // ---- B-frags straight from global (volatile -> MALL), ping-pong ----
        // lane (quad,l15) needs h[b][kk*32 + quad*8 .. +7] - contiguous 16B.
        const bf16* hb_base = hin + (size_t)b * HD_ + quad * 8;
        f32x4 acc0 = f32x4{0.f, 0.f, 0.f, 0.f};
        f32x4 acc1 = f32x4{0.f, 0.f, 0.f, 0.f};
        bf16x8 hb[2][8];
#pragma unroll
        for (int i = 0; i < 8; ++i)
            hb[0][i] = vload8(hb_base + i * 32);
#pragma unroll
        for (int grp = 0; grp < 4; ++grp) {
            if (grp < 3) {
#pragma unroll
                for (int i = 0; i < 8; ++i)
                    hb[(grp + 1) & 1][i] =
                        vload8(hb_base + (grp + 1) * 256 + i * 32);
            }
#pragma unroll
            for (int i = 0; i < 8; ++i) {
                const bf16x8 bf = hb[grp & 1][i];
                acc0 = __builtin_amdgcn_mfma_f32_16x16x32_bf16(
                    awh[0][grp * 8 + i], bf, acc0, 0, 0, 0);
                acc1 = __builtin_amdgcn_mfma_f32_16x16x32_bf16(
                    awh[1][grp * 8 + i], bf, acc1, 0, 0, 0);
            }
        }

        // ---- activations (own 8 lcols: acc0 -> lcol=quad*4+r, acc1 -> +16) ----
        float v0[4], v1[4];
#pragma unroll
        for (int r = 0; r < 4; ++r) {
            const float p0 = acc0[r] + (float)gx[r];
            const float p1 = acc1[r] + (float)gx[4 + r];
            v0[r] = sigmoid_fast(p0);                              // F or I
            v1[r] = (quad < 2) ? tanh_fast(p1) : sigmoid_fast(p1); // A or O
        }
        // ---- exchange with quad^2 partner (lane ^ 32) ----
        float u0[4], u1[4];
#pragma unroll
        for (int r = 0; r < 4; ++r) {
            u0[r] = __shfl_xor(v0[r], 32, 64);
            u1[r] = __shfl_xor(v1[r], 32, 64);
        }
        const int rsel = 2 * (quad >> 1);
        const float f0 = (quad < 2) ? v0[rsel]     : u0[rsel];
        const float i0 = (quad < 2) ? u0[rsel]     : v0[rsel];
        const float a0 = (quad < 2) ? v1[rsel]     : u1[rsel];
        const float o0 = (quad < 2) ? u1[rsel]     : v1[rsel];
        const float f1 = (quad < 2) ? v0[rsel + 1] : u0[rsel + 1];
        const float i1 = (quad < 2) ? u0[rsel + 1] : v0[rsel + 1];
        const float a1 = (quad < 2) ? v1[rsel + 1] : u1[rsel + 1];
        const float o1 = (quad < 2) ? u1[rsel + 1] : v1[rsel + 1];

        const float cn0 = f0 * c0 + i0 * a0;  c0 = cn0;
        const float cn1 = f1 * c1 + i1 * a1;  c1 = cn1;
        const float h0 = o0 * tanh_fast(cn0);
        const float h1 = o1 * tanh_fast(cn1);

        const int hidx = b * HD_ + blk * UPB + jl0;
        const unsigned int packed =
            (unsigned int)bf16_bits(h0) | ((unsigned int)bf16_bits(h1) << 16);
        *reinterpret_cast<volatile unsigned int*>(hout + hidx) = packed;
        *reinterpret_cast<float2*>(
            out + ((size_t)b * T_ + t) * HD_ + blk * UPB + jl0) =
            make_float2(h0, h1);
        if (t == T_ - 1) {
            *reinterpret_cast<float2*>(out + (size_t)M1_ * HD_ + hidx) =
                make_float2(h0, h1);
            *reinterpret_cast<float2*>(
                out + (size_t)M1_ * HD_ + B_ * HD_ + hidx) =
                make_float2(cn0, cn1);
        }
        // drain h stores to MALL, then publish this (block,wave)'s flag
        __asm__ __volatile__("s_waitcnt vmcnt(0)" ::: "memory");
        if (lane == 0) *myflag = t + 1;
    }
}

// -------------------------------------------------------------- launcher ----
extern "C" void kernel_launch(void* const* d_in, const int* in_sizes, int n_in,
                              void* d_out, int out_size, void* d_ws, size_t ws_size,
                              hipStream_t stream) {
    const float* x  = (const float*)d_in[0];
    const float* Wi = (const float*)d_in[1];
    const float* bi = (const float*)d_in[2];
    const float* Wh = (const float*)d_in[3];
    const float* bh = (const float*)d_in[4];
    float* out = (float*)d_out;

    char* ws = (char*)d_ws;
    size_t off = 0;
    bf16* xb     = (bf16*)(ws + off); off += (size_t)M1_ * ID_ * 2;       // 16 MB
    bf16* wiT    = (bf16*)(ws + off); off += (size_t)NG_ * ID_ * 2;       // 4 MB
    bf16* whT    = (bf16*)(ws + off); off += (size_t)NG_ * HD_ * 2;       // 8 MB
    bf16* gates3 = (bf16*)(ws + off); off += (size_t)T_ * B_ * NG_ * 2;   // 128 MB
    bf16* hbuf   = (bf16*)(ws + off); off += (size_t)2 * B_ * HD_ * 2;    // 256 KB
    int* flags   = (int*)(ws + off);  off += (size_t)NBLK * 4 * 16 * 4;   // 32 KB

    prep_kernel<<<8192, 256, 0, stream>>>(x, Wi, Wh, xb, wiT, whT, hbuf, flags);
    gates_gemm_kernel<<<dim3(128, 32), 256, 0, stream>>>(xb, wiT, bi, bh, gates3);

    // Plain launch: 128 blocks on 256 CUs are always co-resident; t=0 needs
    // no waiting, so dispatch-time skew is benign. (Coop API dropped - its
    // silent launch failure was the round-4 zero-output signature suspect.)
    lstm_persistent_kernel<<<dim3(NBLK), dim3(256), 0, stream>>>(
        gates3, whT, hbuf, out, flags);
}

// Round 6
// 2933.592 us; speedup vs baseline: 1.3905x; 1.0161x over previous
//
#include <hip/hip_runtime.h>
#include <hip/hip_bf16.h>

// LSTM B=64, T=256, ID=512, HD=1024. Gates F,I,A,O.
// Round 6: round-5 structure + Wh fragments PINNED in VGPRs via asm barrier
// (round 5's VGPR_Count=156 proved the compiler was re-loading all 64 Wh
// fragments from global every timestep - on the serial critical path).

#define B_  64
#define T_  256
#define ID_ 512
#define HD_ 1024
#define NG_ 4096
#define M1_ (B_ * T_)
#define NBLK 128
#define UPB  8

typedef __bf16 bf16x8 __attribute__((ext_vector_type(8)));
typedef float  f32x4  __attribute__((ext_vector_type(4)));
typedef int    i32x4  __attribute__((ext_vector_type(4)));
typedef short  s16x4  __attribute__((ext_vector_type(4)));

using bf16 = __hip_bfloat16;

__device__ __forceinline__ float sigmoid_fast(float x) {
    return 1.0f / (1.0f + __expf(-x));
}
__device__ __forceinline__ float tanh_fast(float x) {
    return 1.0f - 2.0f / (__expf(2.0f * x) + 1.0f);
}
__device__ __forceinline__ unsigned short bf16_bits(float x) {
    union { bf16 h; unsigned short u; } cv;
    cv.h = __float2bfloat16(x);
    return cv.u;
}
__device__ __forceinline__ bf16x8 vload8(const bf16* p) {
    union { i32x4 i; bf16x8 h; } cv;
    cv.i = *reinterpret_cast<const volatile i32x4*>(p);
    return cv.h;
}
__device__ __forceinline__ bf16x8 as_bf16x8(i32x4 v) {
    union { i32x4 i; bf16x8 h; } cv;
    cv.i = v;
    return cv.h;
}

// ---------------------------------------------------------------- prep ----
__global__ __launch_bounds__(256) void prep_kernel(
    const float* __restrict__ x, const float* __restrict__ Wi,
    const float* __restrict__ Wh, bf16* __restrict__ xb,
    bf16* __restrict__ wiT, bf16* __restrict__ whT,
    bf16* __restrict__ hbuf, int* __restrict__ flags) {
    const int tid = blockIdx.x * 256 + threadIdx.x;  // [0, 2097152)

    if (tid < NBLK * 4 * 16) flags[tid] = 0;          // 512 flag lines
    if (tid < (B_ * HD_) / 4)                         // h[-1] = 0 (buf0)
        *reinterpret_cast<s16x4*>(hbuf + (size_t)tid * 4) = s16x4{0, 0, 0, 0};

    const float4 v = reinterpret_cast<const float4*>(x)[tid];
    bf16 tmp[4] = { __float2bfloat16(v.x), __float2bfloat16(v.y),
                    __float2bfloat16(v.z), __float2bfloat16(v.w) };
    *reinterpret_cast<s16x4*>(xb + 4 * (size_t)tid) =
        *reinterpret_cast<s16x4*>(tmp);

    {   // WiT[n][k] = Wi[k][n]
        const int n = tid >> 9, k = tid & 511;
        wiT[tid] = __float2bfloat16(Wi[(size_t)k * NG_ + n]);
    }
    for (int e = 0; e < 2; ++e) {  // WhT[n][k] = Wh[k][n]
        const int idx = 2 * tid + e;
        const int n = idx >> 10, k = idx & 1023;
        whT[idx] = __float2bfloat16(Wh[(size_t)k * NG_ + n]);
    }
}

// ---------------------------------------------------- phase-1 gates GEMM ----
// gates3 layout: [t][blk][tid(256)][8] bf16, e = nt*4+r in step-MFMA acc order.
__global__ __launch_bounds__(256) void gates_gemm_kernel(
    const bf16* __restrict__ xb, const bf16* __restrict__ wiT,
    const float* __restrict__ bi, const float* __restrict__ bh,
    bf16* __restrict__ gates3) {
    __shared__ __align__(16) bf16 As[128 * 40];
    __shared__ __align__(16) bf16 Bs[128 * 40];
    const int tid  = threadIdx.x;
    const int lane = tid & 63, wave = tid >> 6;
    const int wm = wave >> 1, wn = wave & 1;
    const int l15 = lane & 15, quad = lane >> 4;
    const int row0 = blockIdx.x * 128, col0 = blockIdx.y * 128;

    f32x4 acc[4][4];
    for (int i = 0; i < 4; ++i)
        for (int j = 0; j < 4; ++j) acc[i][j] = f32x4{0.f, 0.f, 0.f, 0.f};

    for (int kt = 0; kt < ID_ / 32; ++kt) {
        const int k0 = kt * 32;
        for (int L = tid; L < 512; L += 256) {
            const int r = L >> 2, s = L & 3;
            *reinterpret_cast<i32x4*>(&As[r * 40 + s * 8]) =
                *reinterpret_cast<const i32x4*>(xb + (size_t)(row0 + r) * ID_ + k0 + s * 8);
            *reinterpret_cast<i32x4*>(&Bs[r * 40 + s * 8]) =
                *reinterpret_cast<const i32x4*>(wiT + (size_t)(col0 + r) * ID_ + k0 + s * 8);
        }
        __syncthreads();
        bf16x8 af[4], bfv[4];
        for (int mt = 0; mt < 4; ++mt)
            af[mt] = *reinterpret_cast<const bf16x8*>(
                &As[(wm * 64 + mt * 16 + l15) * 40 + quad * 8]);
        for (int nt = 0; nt < 4; ++nt)
            bfv[nt] = *reinterpret_cast<const bf16x8*>(
                &Bs[(wn * 64 + nt * 16 + l15) * 40 + quad * 8]);
        for (int mt = 0; mt < 4; ++mt)
            for (int nt = 0; nt < 4; ++nt)
                acc[mt][nt] = __builtin_amdgcn_mfma_f32_16x16x32_bf16(
                    af[mt], bfv[nt], acc[mt][nt], 0, 0, 0);
        __syncthreads();
    }
    // epilogue: +(bi+bh), store to gates3 in persistent-kernel acc order
    for (int mt = 0; mt < 4; ++mt) {
        for (int nt = 0; nt < 4; ++nt) {
            const int cg = col0 + wn * 64 + nt * 16 + l15;
            const int g = cg >> 10, u = cg & 1023;
            const int blk = u >> 3, jl = u & 7;
            const int lcol = g * 8 + jl;               // m-index in step MFMA
            const int nt2 = lcol >> 4, q2 = (lcol >> 2) & 3, r2 = lcol & 3;
            const int e = nt2 * 4 + r2;
            const float bias = bi[cg] + bh[cg];
            for (int r = 0; r < 4; ++r) {
                const int rg = row0 + wm * 64 + mt * 16 + quad * 4 + r;
                const int b = rg >> 8, t = rg & 255;   // row = b*T + t
                const int tid2 = (b >> 4) * 64 + q2 * 16 + (b & 15);
                gates3[(((size_t)t * NBLK + blk) * 256 + tid2) * 8 + e] =
                    __float2bfloat16(acc[mt][nt][r] + bias);
            }
        }
    }
}

// ------------------------------------------------- persistent LSTM steps ----
__global__ __launch_bounds__(256, 1) void lstm_persistent_kernel(
    const bf16* __restrict__ gates3, const bf16* __restrict__ whT,
    bf16* __restrict__ hbuf, float* __restrict__ out, int* __restrict__ flags) {
    const int tid  = threadIdx.x;
    const int lane = tid & 63, w = tid >> 6;
    const int l15 = lane & 15, quad = lane >> 4;
    const int blk = blockIdx.x;                 // hidden units [blk*8, blk*8+8)

    // ---- preload Wh A-fragments and PIN them in VGPRs ----
    // A[m=lcol][k]: lcol = nt*16 + l15 -> whT row (lcol>>3)*HD + blk*8 + (lcol&7)
    i32x4 awh[2][32];
#pragma unroll
    for (int nt = 0; nt < 2; ++nt) {
        const int lcol = nt * 16 + l15;
        const size_t wrow = (size_t)((lcol >> 3) * HD_ + blk * UPB + (lcol & 7));
#pragma unroll
        for (int kk = 0; kk < 32; ++kk)
            awh[nt][kk] = *reinterpret_cast<const i32x4*>(
                whT + wrow * HD_ + kk * 32 + quad * 8);
    }
    // anti-rematerialization barrier: values now opaque -> must stay resident
#pragma unroll
    for (int nt = 0; nt < 2; ++nt)
#pragma unroll
        for (int kk = 0; kk < 32; ++kk)
            asm volatile("" : "+v"(awh[nt][kk]));

    // cell-update map (after shfl_xor(32) pairing quad<->quad^2):
    // thread covers (b = w*16+l15, units jl0, jl0+1)
    const int jl0 = 4 * (quad & 1) + 2 * (quad >> 1);
    const int b = w * 16 + l15;
    float c0 = 0.f, c1 = 0.f;

    // poll map: lane covers flag lines for blocks lane and lane+64, own wave
    volatile int* pf1 = (volatile int*)(flags + ((lane * 4 + w) << 4));
    volatile int* pf2 = (volatile int*)(flags + (((64 + lane) * 4 + w) << 4));
    volatile int* myflag = (volatile int*)(flags + ((blk * 4 + w) << 4));

    for (int t = 0; t < T_; ++t) {
        const bf16* hin  = hbuf + (size_t)(t & 1) * (B_ * HD_);
        bf16*       hout = hbuf + (size_t)((t + 1) & 1) * (B_ * HD_);

        // issue gates_x load early (plain, L2/HBM)
        const bf16x8 gx = *reinterpret_cast<const bf16x8*>(
            gates3 + (((size_t)t * NBLK + blk) * 256 + tid) * 8);

        // wait until all blocks' wave w published h[t-1]
        if (t > 0) {
            while (*pf1 < t) __builtin_amdgcn_s_sleep(1);
            while (*pf2 < t) __builtin_amdgcn_s_sleep(1);
        }

        // ---- B-frags straight from global (volatile -> MALL), ping-pong ----
        // lane (quad,l15) needs h[b][kk*32 + quad*8 .. +7] - contiguous 16B.
        const bf16* hb_base = hin + (size_t)b * HD_ + quad * 8;
        f32x4 acc0 = f32x4{0.f, 0.f, 0.f, 0.f};
        f32x4 acc1 = f32x4{0.f, 0.f, 0.f, 0.f};
        bf16x8 hb[2][8];
#pragma unroll
        for (int i = 0; i < 8; ++i)
            hb[0][i] = vload8(hb_base + i * 32);
#pragma unroll
        for (int grp = 0; grp < 4; ++grp) {
            if (grp < 3) {
#pragma unroll
                for (int i = 0; i < 8; ++i)
                    hb[(grp + 1) & 1][i] =
                        vload8(hb_base + (grp + 1) * 256 + i * 32);
            }
#pragma unroll
            for (int i = 0; i < 8; ++i) {
                const bf16x8 bf = hb[grp & 1][i];
                acc0 = __builtin_amdgcn_mfma_f32_16x16x32_bf16(
                    as_bf16x8(awh[0][grp * 8 + i]), bf, acc0, 0, 0, 0);
                acc1 = __builtin_amdgcn_mfma_f32_16x16x32_bf16(
                    as_bf16x8(awh[1][grp * 8 + i]), bf, acc1, 0, 0, 0);
            }
        }

        // ---- activations (own 8 lcols: acc0 -> lcol=quad*4+r, acc1 -> +16) ----
        float v0[4], v1[4];
#pragma unroll
        for (int r = 0; r < 4; ++r) {
            const float p0 = acc0[r] + (float)gx[r];
            const float p1 = acc1[r] + (float)gx[4 + r];
            v0[r] = sigmoid_fast(p0);                              // F or I
            v1[r] = (quad < 2) ? tanh_fast(p1) : sigmoid_fast(p1); // A or O
        }
        // ---- exchange with quad^2 partner (lane ^ 32) ----
        float u0[4], u1[4];
#pragma unroll
        for (int r = 0; r < 4; ++r) {
            u0[r] = __shfl_xor(v0[r], 32, 64);
            u1[r] = __shfl_xor(v1[r], 32, 64);
        }
        const int rsel = 2 * (quad >> 1);
        const float f0 = (quad < 2) ? v0[rsel]     : u0[rsel];
        const float i0 = (quad < 2) ? u0[rsel]     : v0[rsel];
        const float a0 = (quad < 2) ? v1[rsel]     : u1[rsel];
        const float o0 = (quad < 2) ? u1[rsel]     : v1[rsel];
        const float f1 = (quad < 2) ? v0[rsel + 1] : u0[rsel + 1];
        const float i1 = (quad < 2) ? u0[rsel + 1] : v0[rsel + 1];
        const float a1 = (quad < 2) ? v1[rsel + 1] : u1[rsel + 1];
        const float o1 = (quad < 2) ? u1[rsel + 1] : v1[rsel + 1];

        const float cn0 = f0 * c0 + i0 * a0;  c0 = cn0;
        const float cn1 = f1 * c1 + i1 * a1;  c1 = cn1;
        const float h0 = o0 * tanh_fast(cn0);
        const float h1 = o1 * tanh_fast(cn1);

        const int hidx = b * HD_ + blk * UPB + jl0;
        // out stores first (L2 write-back), h store last (MALL) so the
        // vmcnt(0) drain is dominated by a single MALL store ack.
        *reinterpret_cast<float2*>(
            out + ((size_t)b * T_ + t) * HD_ + blk * UPB + jl0) =
            make_float2(h0, h1);
        if (t == T_ - 1) {
            *reinterpret_cast<float2*>(out + (size_t)M1_ * HD_ + hidx) =
                make_float2(h0, h1);
            *reinterpret_cast<float2*>(
                out + (size_t)M1_ * HD_ + B_ * HD_ + hidx) =
                make_float2(cn0, cn1);
        }
        const unsigned int packed =
            (unsigned int)bf16_bits(h0) | ((unsigned int)bf16_bits(h1) << 16);
        *reinterpret_cast<volatile unsigned int*>(hout + hidx) = packed;
        // drain h store to MALL, then publish this (block,wave)'s flag
        __asm__ __volatile__("s_waitcnt vmcnt(0)" ::: "memory");
        if (lane == 0) *myflag = t + 1;
    }
}

// -------------------------------------------------------------- launcher ----
extern "C" void kernel_launch(void* const* d_in, const int* in_sizes, int n_in,
                              void* d_out, int out_size, void* d_ws, size_t ws_size,
                              hipStream_t stream) {
    const float* x  = (const float*)d_in[0];
    const float* Wi = (const float*)d_in[1];
    const float* bi = (const float*)d_in[2];
    const float* Wh = (const float*)d_in[3];
    const float* bh = (const float*)d_in[4];
    float* out = (float*)d_out;

    char* ws = (char*)d_ws;
    size_t off = 0;
    bf16* xb     = (bf16*)(ws + off); off += (size_t)M1_ * ID_ * 2;       // 16 MB
    bf16* wiT    = (bf16*)(ws + off); off += (size_t)NG_ * ID_ * 2;       // 4 MB
    bf16* whT    = (bf16*)(ws + off); off += (size_t)NG_ * HD_ * 2;       // 8 MB
    bf16* gates3 = (bf16*)(ws + off); off += (size_t)T_ * B_ * NG_ * 2;   // 128 MB
    bf16* hbuf   = (bf16*)(ws + off); off += (size_t)2 * B_ * HD_ * 2;    // 256 KB
    int* flags   = (int*)(ws + off);  off += (size_t)NBLK * 4 * 16 * 4;   // 32 KB

    prep_kernel<<<8192, 256, 0, stream>>>(x, Wi, Wh, xb, wiT, whT, hbuf, flags);
    gates_gemm_kernel<<<dim3(128, 32), 256, 0, stream>>>(xb, wiT, bi, bh, gates3);

    lstm_persistent_kernel<<<dim3(NBLK), dim3(256), 0, stream>>>(
        gates3, whT, hbuf, out, flags);
}